// Round 1
// baseline (160.605 us; speedup 1.0000x reference)
//
#include <hip/hip_runtime.h>

// LTCN layer: NB=64 blocks x K=64 neurons, BATCH=4096, blocks independent.
// R3: 512-thread WGs, 128 batch rows per WG (8 waves x 16-row bands).
//  - Weight re-stage traffic halved vs 64-row tiles (2048 WGs x 64KB).
//  - Dedicated nets LDS buffers (sNo/sNr) remove the WAR hazard on the weight
//    buffers: j!=0 path has ONE barrier total; the nets LDS round-trip is
//    intra-wave (wave w writes rows [16w,16w+16) and reads the same band).
//  - j==0 pre-stages all 4 W_in chunks into sWf+sNo+sNr (no restage loop);
//    needs one extra barrier before nets overwrite the chunk space.
//  - ye (epilogue y re-read, L2-hot) issued right after phase-2 MFMAs so its
//    latency hides under tanh + net writes.
// LDS: 4x(64x72) weights + 2x(128x72) nets = 73.7KB -> 2 WG/CU (wave-capped
// at 2 anyway: 512 thr, VGPR<=128 via __launch_bounds__(512,4) -> 16 waves/CU).

#define IN_DIM 256
#define K 64
#define NB 64
#define BATCH 4096
#define NTOT (NB * K)          // 4096
#define DTC 0.05f
#define TAU_EPS 1e-6f
#define LDSTR 72               // padded LDS row stride (bf16), 16B-aligned rows

typedef __bf16 bf16;
typedef bf16 bf16x8 __attribute__((ext_vector_type(8)));
typedef bf16 bf16x4 __attribute__((ext_vector_type(4)));
typedef float f32x4 __attribute__((ext_vector_type(4)));

__device__ __forceinline__ float fast_tanh(float x) {
    float e = __expf(2.0f * x);
    return 1.0f - 2.0f * __builtin_amdgcn_rcpf(e + 1.0f);
}

// Stage a 64x64 f32 tile (row stride gstride) into bf16 LDS (stride LDSTR).
// 512-thread version: 2 float4s per thread.
__device__ __forceinline__ void stage64(bf16* __restrict__ dst,
                                        const float* __restrict__ src,
                                        int gstride, int tid) {
#pragma unroll
    for (int it = 0; it < 2; ++it) {
        int idx = it * 512 + tid;
        int r = idx >> 4;
        int c4 = idx & 15;
        float4 v = *(const float4*)(src + r * gstride + (c4 << 2));
        bf16x4 p = { (bf16)v.x, (bf16)v.y, (bf16)v.z, (bf16)v.w };
        *(bf16x4*)(dst + r * LDSTR + (c4 << 2)) = p;
    }
}

// Load one 64-wide A-operand row slice straight into two bf16x8 fragments.
// rowp points at (row, col0 + quad*8); frags cover k = 0..31 and 32..63.
__device__ __forceinline__ void load_afrag(const float* __restrict__ rowp,
                                           bf16x8& f0, bf16x8& f1) {
    float4 a0 = *(const float4*)(rowp);
    float4 a1 = *(const float4*)(rowp + 4);
    float4 a2 = *(const float4*)(rowp + 32);
    float4 a3 = *(const float4*)(rowp + 36);
    f0 = (bf16x8){ (bf16)a0.x, (bf16)a0.y, (bf16)a0.z, (bf16)a0.w,
                   (bf16)a1.x, (bf16)a1.y, (bf16)a1.z, (bf16)a1.w };
    f1 = (bf16x8){ (bf16)a2.x, (bf16)a2.y, (bf16)a2.z, (bf16)a2.w,
                   (bf16)a3.x, (bf16)a3.y, (bf16)a3.z, (bf16)a3.w };
}

__global__ __launch_bounds__(512, 4)
void ltcn_kernel(const float* __restrict__ y, const float* __restrict__ u_t,
                 const float* __restrict__ tau_raw,
                 const float* __restrict__ W_in_w, const float* __restrict__ W_in_b,
                 const float* __restrict__ W_fwd_w, const float* __restrict__ W_fwd_b,
                 const float* __restrict__ W_rec_w, const float* __restrict__ W_rec_b,
                 const float* __restrict__ E_l, const float* __restrict__ E_l_r,
                 float* __restrict__ out) {
    __shared__ bf16 sWf [64 * LDSTR];   // W_fwd / W_in chunk 0
    __shared__ bf16 sWr [64 * LDSTR];   // W_rec
    __shared__ bf16 sEl [64 * LDSTR];
    __shared__ bf16 sElr[64 * LDSTR];
    __shared__ bf16 sNo [128 * LDSTR];  // net_out (j==0: W_in chunks 1,2 first)
    __shared__ bf16 sNr [128 * LDSTR];  // net_rec (j==0: W_in chunk 3 first)
    __shared__ float sInvTau[64], sBf[64], sBr[64];

    const int tid  = threadIdx.x;
    const int j    = blockIdx.y;
    const int b0   = blockIdx.x * 128;
    const int wave = tid >> 6;            // 0..7
    const int lane = tid & 63;
    const int quad = lane >> 4;
    const int l16  = lane & 15;
    const int am   = wave * 16 + l16;     // A-fragment row within 128-row tile

    // ---- Phase 1: issue everything independent up front ----
    stage64(sWr,  W_rec_w + (size_t)j * K * K, K, tid);
    stage64(sEl,  E_l     + (size_t)j * K * K, K, tid);
    stage64(sElr, E_l_r   + (size_t)j * K * K, K, tid);

    bf16x8 yc0, yc1;                      // y_cur A fragments (rec GEMM)
    load_afrag(y + (size_t)(b0 + am) * NTOT + j * K + quad * 8, yc0, yc1);

    bf16x8 yp0, yp1;                      // y_prev or u_t chunk fragments
    if (j != 0) {
        stage64(sWf, W_fwd_w + (size_t)(j - 1) * K * K, K, tid);
        load_afrag(y + (size_t)(b0 + am) * NTOT + (j - 1) * K + quad * 8, yp0, yp1);
    } else {
        stage64(sWf,              W_in_w,       IN_DIM, tid);  // cols 0..63
        stage64(sNo,              W_in_w + 64,  IN_DIM, tid);  // cols 64..127
        stage64(sNo + 64 * LDSTR, W_in_w + 128, IN_DIM, tid);  // cols 128..191
        stage64(sNr,              W_in_w + 192, IN_DIM, tid);  // cols 192..255
        load_afrag(u_t + (size_t)(b0 + am) * IN_DIM + quad * 8, yp0, yp1);
    }
    if (tid < 64) {
        float x = tau_raw[j * K + tid];
        float sp = (x > 15.0f) ? x : log1pf(__expf(x));
        sInvTau[tid] = 1.0f / (sp + TAU_EPS);
        sBf[tid] = (j == 0) ? W_in_b[tid] : W_fwd_b[(j - 1) * K + tid];
        sBr[tid] = W_rec_b[j * K + tid];
    }
    __syncthreads();   // the ONLY barrier on the j!=0 path

    // ---- Phase 2: fwd + rec GEMMs ----
    f32x4 accF[4] = {}, accR[4] = {};
    const int boff = quad * 8;
#pragma unroll
    for (int ct = 0; ct < 4; ++ct) {
        const bf16* br = sWr + (ct * 16 + l16) * LDSTR + boff;
        accR[ct] = __builtin_amdgcn_mfma_f32_16x16x32_bf16(yc0, *(const bf16x8*)br,        accR[ct], 0, 0, 0);
        accR[ct] = __builtin_amdgcn_mfma_f32_16x16x32_bf16(yc1, *(const bf16x8*)(br + 32), accR[ct], 0, 0, 0);
    }
    if (j != 0) {
#pragma unroll
        for (int ct = 0; ct < 4; ++ct) {
            const bf16* bw = sWf + (ct * 16 + l16) * LDSTR + boff;
            accF[ct] = __builtin_amdgcn_mfma_f32_16x16x32_bf16(yp0, *(const bf16x8*)bw,        accF[ct], 0, 0, 0);
            accF[ct] = __builtin_amdgcn_mfma_f32_16x16x32_bf16(yp1, *(const bf16x8*)(bw + 32), accF[ct], 0, 0, 0);
        }
    } else {
        const bf16* chunkB[4] = { sWf, sNo, sNo + 64 * LDSTR, sNr };
#pragma unroll
        for (int kc = 0; kc < 4; ++kc) {
            if (kc)
                load_afrag(u_t + (size_t)(b0 + am) * IN_DIM + kc * 64 + quad * 8, yp0, yp1);
#pragma unroll
            for (int ct = 0; ct < 4; ++ct) {
                const bf16* bw = chunkB[kc] + (ct * 16 + l16) * LDSTR + boff;
                accF[ct] = __builtin_amdgcn_mfma_f32_16x16x32_bf16(yp0, *(const bf16x8*)bw,        accF[ct], 0, 0, 0);
                accF[ct] = __builtin_amdgcn_mfma_f32_16x16x32_bf16(yp1, *(const bf16x8*)(bw + 32), accF[ct], 0, 0, 0);
            }
        }
    }

    // ---- ye prefetch (L2-hot re-read) — hides under tanh + net writes ----
    float ye[4][4];
    const float* yep = y + (size_t)(b0 + wave * 16 + quad * 4) * NTOT + (size_t)j * K + l16;
#pragma unroll
    for (int ct = 0; ct < 4; ++ct)
#pragma unroll
        for (int r = 0; r < 4; ++r)
            ye[ct][r] = yep[(size_t)r * NTOT + ct * 16];

    // ---- Phase 3: tanh (in regs), decay terms stay resident ----
    float absum[4][4];
#pragma unroll
    for (int ct = 0; ct < 4; ++ct) {
        float bfv = sBf[ct * 16 + l16];
        float brv = sBr[ct * 16 + l16];
#pragma unroll
        for (int r = 0; r < 4; ++r) {
            float no = fast_tanh(accF[ct][r] + bfv);
            float nr = fast_tanh(accR[ct][r] + brv);
            accF[ct][r] = no;
            accR[ct][r] = nr;
            absum[ct][r] = fabsf(no) + fabsf(nr);
        }
    }

    if (j == 0) __syncthreads();  // all W_in-chunk B-reads done before overwrite

    // nets: C-layout -> dedicated LDS. Wave w writes rows [16w,16w+16) and
    // reads back the SAME band -> intra-wave, no barrier needed.
#pragma unroll
    for (int ct = 0; ct < 4; ++ct) {
#pragma unroll
        for (int r = 0; r < 4; ++r) {
            int m = wave * 16 + quad * 4 + r;
            int n = ct * 16 + l16;
            sNo[m * LDSTR + n] = (bf16)accF[ct][r];
            sNr[m * LDSTR + n] = (bf16)accR[ct][r];
        }
    }

    // ---- Phase 4: drive GEMM + epilogue ----
    const bf16* aOp = sNo + am * LDSTR + boff;
    const bf16* aRp = sNr + am * LDSTR + boff;
    bf16x8 aO0 = *(const bf16x8*)aOp, aO1 = *(const bf16x8*)(aOp + 32);
    bf16x8 aR0 = *(const bf16x8*)aRp, aR1 = *(const bf16x8*)(aRp + 32);

    f32x4 accD[4] = {};
#pragma unroll
    for (int ct = 0; ct < 4; ++ct) {
        const bf16* bo = sEl  + (ct * 16 + l16) * LDSTR + boff;
        const bf16* br = sElr + (ct * 16 + l16) * LDSTR + boff;
        accD[ct] = __builtin_amdgcn_mfma_f32_16x16x32_bf16(aO0, *(const bf16x8*)bo,        accD[ct], 0, 0, 0);
        accD[ct] = __builtin_amdgcn_mfma_f32_16x16x32_bf16(aO1, *(const bf16x8*)(bo + 32), accD[ct], 0, 0, 0);
        accD[ct] = __builtin_amdgcn_mfma_f32_16x16x32_bf16(aR0, *(const bf16x8*)br,        accD[ct], 0, 0, 0);
        accD[ct] = __builtin_amdgcn_mfma_f32_16x16x32_bf16(aR1, *(const bf16x8*)(br + 32), accD[ct], 0, 0, 0);
    }

    float it4[4];
#pragma unroll
    for (int ct = 0; ct < 4; ++ct) it4[ct] = sInvTau[ct * 16 + l16];

#pragma unroll
    for (int ct = 0; ct < 4; ++ct) {
#pragma unroll
        for (int r = 0; r < 4; ++r) {
            size_t gi = (size_t)(b0 + wave * 16 + quad * 4 + r) * NTOT + j * K + ct * 16 + l16;
            float decay = it4[ct] + absum[ct][r];
            out[gi] = (ye[ct][r] + DTC * accD[ct][r]) * __builtin_amdgcn_rcpf(1.0f + DTC * decay);
        }
    }
}

extern "C" void kernel_launch(void* const* d_in, const int* in_sizes, int n_in,
                              void* d_out, int out_size, void* d_ws, size_t ws_size,
                              hipStream_t stream) {
    const float* y       = (const float*)d_in[0];
    const float* u_t     = (const float*)d_in[1];
    const float* tau_raw = (const float*)d_in[2];
    const float* W_in_w  = (const float*)d_in[3];
    const float* W_in_b  = (const float*)d_in[4];
    const float* W_fwd_w = (const float*)d_in[5];
    const float* W_fwd_b = (const float*)d_in[6];
    const float* W_rec_w = (const float*)d_in[7];
    const float* W_rec_b = (const float*)d_in[8];
    const float* E_l     = (const float*)d_in[9];
    const float* E_l_r   = (const float*)d_in[10];
    float* out = (float*)d_out;

    dim3 grid(BATCH / 128, NB);
    hipLaunchKernelGGL(ltcn_kernel, grid, dim3(512), 0, stream,
                       y, u_t, tau_raw, W_in_w, W_in_b, W_fwd_w, W_fwd_b,
                       W_rec_w, W_rec_b, E_l, E_l_r, out);
}